// Round 13
// baseline (564.805 us; speedup 1.0000x reference)
//
#include <hip/hip_runtime.h>
#include <hip/hip_fp16.h>

typedef _Float16 f16;
typedef _Float16 f16x2 __attribute__((ext_vector_type(2)));
typedef _Float16 f16x8 __attribute__((ext_vector_type(8)));
typedef float f32x4 __attribute__((ext_vector_type(4)));

// Combined projection: rows 0..511 = Wq (8 heads x 64), 512..1023 = Wk,
// 1024..1055 = Ww (V), 1056..1311 = Wb (output). Padded to 1408 rows (128-mult).
#define WC_ROWS 1312
#define WC_PAD 1408

// ---------------- prep: combined weight matrix (f16) + bias (f32) ----------------
__global__ void prep_weights(const float* __restrict__ Wq, const float* __restrict__ bq,
                             const float* __restrict__ Wk, const float* __restrict__ bk,
                             const float* __restrict__ Ww, const float* __restrict__ bw,
                             const float* __restrict__ Wb, const float* __restrict__ bb,
                             f16* __restrict__ Wc, float* __restrict__ bias) {
    int id = blockIdx.x * 256 + threadIdx.x;   // WC_PAD*256 threads
    int j = id >> 8, k = id & 255;
    if (j >= WC_PAD) return;
    float v;
    if (j < 512)       v = Wq[j*256 + k];          // Wq flat [8,64,256]: row h*64+d == j
    else if (j < 1024) v = Wk[(j-512)*256 + k];
    else if (j < 1056) v = Ww[(j-1024)*256 + k];
    else if (j < 1312) v = Wb[(j-1056)*256 + k];
    else               v = 0.f;
    Wc[j*256 + k] = (f16)v;
    if (k == 0) {
        float b;
        if (j < 512)       b = bq[j];
        else if (j < 1024) b = bk[j-512];
        else if (j < 1056) b = bw[j-1024];
        else if (j < 1312) b = bb[j-1056];
        else               b = 0.f;
        bias[j] = b;
    }
}

// ---------------- prep: CSR row starts (edges sorted by src; every row non-empty) --
__global__ void build_rows(const int* __restrict__ src, int E, int n, int* __restrict__ rs) {
    int e = blockIdx.x * 256 + threadIdx.x;
    if (e == 0) rs[n] = E;
    if (e < E) {
        if (e == 0 || src[e] != src[e-1]) rs[src[e]] = e;
    }
}

// ---------------- fused projection GEMM (r6-proven reg-staged version) -------------
// REVERTED from the r9 global_load_lds + raw-s_barrier + counted-vmcnt variant:
// raw __builtin_amdgcn_s_barrier() is NOT a compiler memory fence, so the ds_read
// fragment loads can be hoisted above it — a wave can then read another wave's
// LDS quarter before its async stage landed (timing-dependent; prime suspect for
// the r10/r12 tripwire flakiness). This version uses __syncthreads() (full
// waitcnt+barrier) and register staging: 0 tripwire failures across rounds 1-8.
__device__ __forceinline__ int swz_slot(int row, int c) {
    return row * 4 + (c ^ (row & 3) ^ ((row >> 2) & 3));
}

__device__ __forceinline__ uint4 cvt8(float4 a, float4 b) {
    f16x8 o;
    o[0] = (f16)a.x; o[1] = (f16)a.y; o[2] = (f16)a.z; o[3] = (f16)a.w;
    o[4] = (f16)b.x; o[5] = (f16)b.y; o[6] = (f16)b.z; o[7] = (f16)b.w;
    return __builtin_bit_cast(uint4, o);
}

__launch_bounds__(256)
__global__ void gemm_fused(const float* __restrict__ F, const f16* __restrict__ Wc,
                           const float* __restrict__ bias,
                           f16* __restrict__ Qb, f16* __restrict__ Kb, f16* __restrict__ Vb,
                           float* __restrict__ Out, int n) {
    __shared__ uint4 As4[512];   // 128 rows x 32 k (f16) = 8KB
    __shared__ uint4 Bs4[512];   // 128 rows x 32 k = 8KB
    int t = threadIdx.x;
    int lane = t & 63, w = t >> 6;
    int wm = w >> 1, wn = w & 1;
    long m0 = (long)blockIdx.y * 128;
    int n0 = blockIdx.x * 128;

    f32x4 acc[4][4];
    #pragma unroll
    for (int i = 0; i < 4; i++)
        #pragma unroll
        for (int j = 0; j < 4; j++)
            acc[i][j] = (f32x4){0.f, 0.f, 0.f, 0.f};

    int lrow = t >> 2, lc = t & 3;
    long row0 = m0 + lrow, row1 = m0 + 64 + lrow;
    const float4* Fg0 = (const float4*)(F + row0 * 256 + lc * 8);   // 8 f32 per thread
    const float4* Fg1 = (const float4*)(F + row1 * 256 + lc * 8);
    const uint4*  Bg0 = (const uint4*)(Wc + (long)(n0 + lrow) * 256 + lc * 8);
    const uint4*  Bg1 = (const uint4*)(Wc + (long)(n0 + 64 + lrow) * 256 + lc * 8);
    bool ok0 = row0 < n, ok1 = row1 < n;
    int ws0 = swz_slot(lrow, lc);
    int ws1 = swz_slot(lrow + 64, lc);
    int csw = (lane >> 4) ^ (lane & 3) ^ ((lane >> 2) & 3);
    int arow = wm * 64 + (lane & 15);
    int brow = wn * 64 + (lane & 15);

    float4 fa0 = {}, fb0 = {}, fa1 = {}, fb1 = {};
    if (ok0) { fa0 = Fg0[0]; fb0 = Fg0[1]; }
    if (ok1) { fa1 = Fg1[0]; fb1 = Fg1[1]; }
    uint4 rb0 = Bg0[0], rb1 = Bg1[0];
    for (int kt = 0; kt < 8; ++kt) {
        if (kt) __syncthreads();
        As4[ws0] = cvt8(fa0, fb0);
        As4[ws1] = cvt8(fa1, fb1);
        Bs4[ws0] = rb0;
        Bs4[ws1] = rb1;
        __syncthreads();
        if (kt < 7) {            // prefetch next K-slice (k step 32 f32 = 8 float4)
            if (ok0) { fa0 = Fg0[(kt + 1) * 8]; fb0 = Fg0[(kt + 1) * 8 + 1]; }
            if (ok1) { fa1 = Fg1[(kt + 1) * 8]; fb1 = Fg1[(kt + 1) * 8 + 1]; }
            rb0 = Bg0[(kt + 1) * 4];
            rb1 = Bg1[(kt + 1) * 4];
        }
        f16x8 af[4], bf[4];
        const f16x8* Ap = (const f16x8*)As4;
        const f16x8* Bp = (const f16x8*)Bs4;
        #pragma unroll
        for (int i = 0; i < 4; i++) af[i] = Ap[(arow + i * 16) * 4 + csw];
        #pragma unroll
        for (int j = 0; j < 4; j++) bf[j] = Bp[(brow + j * 16) * 4 + csw];
        #pragma unroll
        for (int i = 0; i < 4; i++)
            #pragma unroll
            for (int j = 0; j < 4; j++)
                acc[i][j] = __builtin_amdgcn_mfma_f32_16x16x32_f16(af[i], bf[j], acc[i][j], 0, 0, 0);
    }

    // epilogue: C row = (lane>>4)*4 + reg (M), col = lane&15 (N)  [m89-verified]
    #pragma unroll
    for (int i = 0; i < 4; i++) {
        long gmb = m0 + wm * 64 + i * 16 + (lane >> 4) * 4;
        #pragma unroll
        for (int j = 0; j < 4; j++) {
            int gn = n0 + wn * 64 + j * 16 + (lane & 15);
            float bv = bias[gn];
            #pragma unroll
            for (int r = 0; r < 4; r++) {
                long gm = gmb + r;
                if (gm >= n) continue;
                float v = acc[i][j][r] + bv;
                if (gn < 512)       Qb[gm * 512 + gn] = (f16)v;
                else if (gn < 1024) Kb[gm * 512 + (gn - 512)] = (f16)v;
                else if (gn < 1056) Vb[gm * 32 + (gn - 1024)] = (f16)v;
                else if (gn < 1312) Out[gm * 256 + (gn - 1056)] = v;
                // gn in [1312,1408): padding, no write
            }
        }
    }
}

// ---------------- f16x2 dot helper ----------------
__device__ __forceinline__ float fd2(unsigned a, unsigned b, float c) {
#if defined(__has_builtin)
#if __has_builtin(__builtin_amdgcn_fdot2)
    return __builtin_amdgcn_fdot2(__builtin_bit_cast(f16x2, a), __builtin_bit_cast(f16x2, b), c, false);
#else
    f16x2 x = __builtin_bit_cast(f16x2, a), y = __builtin_bit_cast(f16x2, b);
    return c + (float)x[0] * (float)y[0] + (float)x[1] * (float)y[1];
#endif
#else
    f16x2 x = __builtin_bit_cast(f16x2, a), y = __builtin_bit_cast(f16x2, b);
    return c + (float)x[0] * (float)y[0] + (float)x[1] * (float)y[1];
#endif
}

// ---------------- phase A: edge-parallel scores, head-phased + [h][Epad] sE --------
// h = bid&7 (XCD-resident head stream), e = (bid>>3)*256+tid. r11 proved the
// working-set win (FETCH 794->493MB) but its [e][h] store was a 2B stride-16B
// scatter (WRITE 26->206MB RMW). sE is [h][Epad]: store coalesced 128B/wave.
__launch_bounds__(256)
__global__ void edge_scores(const int* __restrict__ srcA, const int* __restrict__ dstA,
                            const f16* __restrict__ Qb, const f16* __restrict__ Kb,
                            f16* __restrict__ sE, int E, int Epad) {
    int bid = blockIdx.x;
    int h = bid & 7;                          // head = XCD (round-robin dispatch)
    int e = (bid >> 3) * 256 + threadIdx.x;   // contiguous src-sorted edge stream
    if (e >= E) return;
    int s = srcA[e], d = dstA[e];
    const uint4* qp = (const uint4*)(Qb + (size_t)s * 512 + h * 64);
    const uint4* kp = (const uint4*)(Kb + (size_t)d * 512 + h * 64);
    uint4 kv[8], qv[8];
    #pragma unroll
    for (int c = 0; c < 8; c++) kv[c] = kp[c];   // random gather (the fundamental traffic)
    #pragma unroll
    for (int c = 0; c < 8; c++)
        asm volatile("" : "+v"(kv[c].x), "+v"(kv[c].y), "+v"(kv[c].z), "+v"(kv[c].w));
    #pragma unroll
    for (int c = 0; c < 8; c++) qv[c] = qp[c];   // L1/L2-hot stream
    float a0 = 0.f, a1 = 0.f;
    #pragma unroll
    for (int c = 0; c < 8; c += 2) {
        a0 = fd2(qv[c].x,   kv[c].x,   a0);
        a0 = fd2(qv[c].y,   kv[c].y,   a0);
        a0 = fd2(qv[c].z,   kv[c].z,   a0);
        a0 = fd2(qv[c].w,   kv[c].w,   a0);
        a1 = fd2(qv[c+1].x, kv[c+1].x, a1);
        a1 = fd2(qv[c+1].y, kv[c+1].y, a1);
        a1 = fd2(qv[c+1].z, kv[c+1].z, a1);
        a1 = fd2(qv[c+1].w, kv[c+1].w, a1);
    }
    sE[(size_t)h * Epad + e] = (f16)(a0 + a1);   // coalesced 128B/wave
}

// ---------------- phase B: row-parallel softmax + MFMA aggregation -----------------
// r9-exact two-pass structure; only the sE access adapts to [h][Epad] (8 scalar
// f16 loads, each 2B/lane consecutive = coalesced). asm ""::"memory" fences
// (zero runtime cost) pin LDS write->read ordering against any type-punned
// aliasing reorder — defensive hardening after the r10/r12 tripwire flakiness.
__launch_bounds__(256)
__global__ void edge_agg(const int* __restrict__ rs, const int* __restrict__ dstA,
                         const f16* __restrict__ sE, const f16* __restrict__ Vb,
                         float* __restrict__ Out, int n, int Epad) {
    __shared__ __align__(16) f16 P_lds[4][16][64];
    __shared__ int dS[4][64];
    int w = threadIdx.x >> 6, lane = threadIdx.x & 63;
    int row = blockIdx.x * 4 + w;
    if (row >= n) return;
    int e0 = rs[row], deg = rs[row + 1] - e0;
    {   // zero A-frag rows 8..15 (read by MFMA, results discarded; avoid NaN garbage)
        f16x8 z = {};
        *(f16x8*)&P_lds[w][8 + (lane >> 3)][(lane & 7) * 8] = z;
    }
    asm volatile("" ::: "memory");
    // pass 1: global per-head max
    float pm[8];
    #pragma unroll
    for (int h = 0; h < 8; h++) pm[h] = -1e30f;
    for (int base = 0; base < deg; base += 64) {
        bool act = lane < deg - base;
        int ee = e0 + base + (act ? lane : 0);
        #pragma unroll
        for (int h = 0; h < 8; h++) {
            float sv = act ? (float)sE[(size_t)h * Epad + ee] : -1e30f;
            pm[h] = fmaxf(pm[h], sv);
        }
    }
    float m[8];
    #pragma unroll
    for (int h = 0; h < 8; h++) {
        float v = pm[h];
        #pragma unroll
        for (int off = 1; off < 64; off <<= 1) v = fmaxf(v, __shfl_xor(v, off));
        m[h] = v;
    }
    // pass 2: P, V-MFMA, ones-MFMA (denominator)
    f32x4 acc0 = {}, acc1 = {}, accl = {};
    int ec0 = (lane >> 4) * 8, h_a = lane & 15, hsel = (lane >> 4) & 1;
    f16x8 ones;
    #pragma unroll
    for (int j = 0; j < 8; j++) ones[j] = (f16)1.f;
    for (int base = 0; base < deg; base += 64) {
        int nE = deg - base; if (nE > 64) nE = 64;
        bool act = lane < nE;
        int ee = e0 + base + (act ? lane : 0);
        int d = dstA[ee];
        dS[w][lane] = d;
        #pragma unroll
        for (int h = 0; h < 8; h++) {
            float sv = act ? (float)sE[(size_t)h * Epad + ee] : 0.f;
            float p = act ? __expf(sv - m[h]) : 0.f;
            P_lds[w][h][lane ^ (h << 3)] = (f16)p;
        }
        asm volatile("" ::: "memory");   // LDS writes ordered before the punned reads
        // A-frags: P[h][k], k = ks*32 + ec0 + j (XOR-decoded contiguous b128)
        f16x8 a0 = *(const f16x8*)&P_lds[w][h_a][(ec0)      ^ ((h_a & 7) << 3)];
        f16x8 a1 = *(const f16x8*)&P_lds[w][h_a][(32 + ec0) ^ ((h_a & 7) << 3)];
        // B-frags: V[e][dim], dim = nh*16 + (lane&15)
        f16x8 bf0a, bf0b, bf1a, bf1b;
        #pragma unroll
        for (int j = 0; j < 8; j++) {
            int dd0 = dS[w][ec0 + j];
            int dd1 = dS[w][32 + ec0 + j];
            const f16* vp0 = Vb + (size_t)dd0 * 32 + (lane & 15);
            const f16* vp1 = Vb + (size_t)dd1 * 32 + (lane & 15);
            bf0a[j] = vp0[0];  bf0b[j] = vp0[16];
            bf1a[j] = vp1[0];  bf1b[j] = vp1[16];
        }
        asm volatile("" ::: "memory");   // reads complete before next tile's writes
        acc0 = __builtin_amdgcn_mfma_f32_16x16x32_f16(a0, bf0a, acc0, 0, 0, 0);
        acc0 = __builtin_amdgcn_mfma_f32_16x16x32_f16(a1, bf1a, acc0, 0, 0, 0);
        acc1 = __builtin_amdgcn_mfma_f32_16x16x32_f16(a0, bf0b, acc1, 0, 0, 0);
        acc1 = __builtin_amdgcn_mfma_f32_16x16x32_f16(a1, bf1b, acc1, 0, 0, 0);
        accl = __builtin_amdgcn_mfma_f32_16x16x32_f16(a0, ones, accl, 0, 0, 0);
        accl = __builtin_amdgcn_mfma_f32_16x16x32_f16(a1, ones, accl, 0, 0, 0);
    }
    // epilogue: D row = hsel*4 + r = head, col = lane&15; out dim = h*32 + nh*16 + col
    if (lane < 32) {
        float* op = Out + (size_t)row * 256 + (lane & 15);
        #pragma unroll
        for (int r = 0; r < 4; r++) {
            int h = hsel * 4 + r;
            float inv = 1.f / accl[r];
            op[h * 32]      += acc0[r] * inv;
            op[h * 32 + 16] += acc1[r] * inv;
        }
    }
}

// ---------------- launch ----------------
extern "C" void kernel_launch(void* const* d_in, const int* in_sizes, int n_in,
                              void* d_out, int out_size, void* d_ws, size_t ws_size,
                              hipStream_t stream) {
    const float* F  = (const float*)d_in[0];
    const int*   ei = (const int*)d_in[1];
    const float* Wq = (const float*)d_in[2];
    const float* bq = (const float*)d_in[3];
    const float* Wk = (const float*)d_in[4];
    const float* bk = (const float*)d_in[5];
    const float* Ww = (const float*)d_in[6];
    const float* bw = (const float*)d_in[7];
    const float* Wb = (const float*)d_in[8];
    const float* bb = (const float*)d_in[9];
    int n = in_sizes[0] / 256;       // 50000
    int E = in_sizes[1] / 2;
    const int* srcA = ei;
    const int* dstA = ei + E;
    int n_pad = (n + 127) & ~127;
    int Epad = (E + 63) & ~63;

    // workspace carve-out (~133 MB)
    char* wp = (char*)d_ws;
    auto alloc = [&](size_t bytes) { void* p = wp; wp += (bytes + 255) & ~255ull; return p; };
    f16*   sE   = (f16*)alloc((size_t)Epad * 8 * 2);
    f16*   Wc   = (f16*)alloc((size_t)WC_PAD * 256 * 2);
    float* bias = (float*)alloc((size_t)WC_PAD * 4);
    f16*   Qb   = (f16*)alloc((size_t)n * 512 * 2);
    f16*   Kb   = (f16*)alloc((size_t)n * 512 * 2);
    f16*   Vb   = (f16*)alloc((size_t)n * 32 * 2);
    int*   rs   = (int*)alloc((size_t)(n + 1) * 4);
    float* Out  = (float*)d_out;

    prep_weights<<<WC_PAD, 256, 0, stream>>>(Wq, bq, Wk, bk, Ww, bw, Wb, bb, Wc, bias);
    build_rows<<<(E + 255) / 256, 256, 0, stream>>>(srcA, E, n, rs);
    dim3 g(WC_PAD / 128, n_pad / 128);   // N fastest: A-panel L2-reuse, B L2-resident
    gemm_fused<<<g, 256, 0, stream>>>(F, Wc, bias, Qb, Kb, Vb, Out, n);
    int wgph = (E + 255) / 256;          // workgroups per head
    edge_scores<<<8 * wgph, 256, 0, stream>>>(srcA, dstA, Qb, Kb, sE, E, Epad);
    edge_agg<<<(n + 3) / 4, 256, 0, stream>>>(rs, dstA, sE, Vb, Out, n, Epad);
}

// Round 14
// 488.705 us; speedup vs baseline: 1.1557x; 1.1557x over previous
//
#include <hip/hip_runtime.h>
#include <hip/hip_fp16.h>

typedef _Float16 f16;
typedef _Float16 f16x2 __attribute__((ext_vector_type(2)));
typedef _Float16 f16x8 __attribute__((ext_vector_type(8)));
typedef float f32x4 __attribute__((ext_vector_type(4)));

// Combined projection: rows 0..511 = Wq (8 heads x 64), 512..1023 = Wk,
// 1024..1055 = Ww (V), 1056..1311 = Wb (output). Padded to 1408 rows (128-mult).
#define WC_ROWS 1312
#define WC_PAD 1408

// ---------------- prep: combined weight matrix (f16) + bias (f32) ----------------
__global__ void prep_weights(const float* __restrict__ Wq, const float* __restrict__ bq,
                             const float* __restrict__ Wk, const float* __restrict__ bk,
                             const float* __restrict__ Ww, const float* __restrict__ bw,
                             const float* __restrict__ Wb, const float* __restrict__ bb,
                             f16* __restrict__ Wc, float* __restrict__ bias) {
    int id = blockIdx.x * 256 + threadIdx.x;   // WC_PAD*256 threads
    int j = id >> 8, k = id & 255;
    if (j >= WC_PAD) return;
    float v;
    if (j < 512)       v = Wq[j*256 + k];          // Wq flat [8,64,256]: row h*64+d == j
    else if (j < 1024) v = Wk[(j-512)*256 + k];
    else if (j < 1056) v = Ww[(j-1024)*256 + k];
    else if (j < 1312) v = Wb[(j-1056)*256 + k];
    else               v = 0.f;
    Wc[j*256 + k] = (f16)v;
    if (k == 0) {
        float b;
        if (j < 512)       b = bq[j];
        else if (j < 1024) b = bk[j-512];
        else if (j < 1056) b = bw[j-1024];
        else if (j < 1312) b = bb[j-1056];
        else               b = 0.f;
        bias[j] = b;
    }
}

// ---------------- prep: CSR row starts (edges sorted by src; every row non-empty) --
__global__ void build_rows(const int* __restrict__ src, int E, int n, int* __restrict__ rs) {
    int e = blockIdx.x * 256 + threadIdx.x;
    if (e == 0) rs[n] = E;
    if (e < E) {
        if (e == 0 || src[e] != src[e-1]) rs[src[e]] = e;
    }
}

// ---------------- fused projection GEMM (r6-proven reg-staged version) -------------
// __syncthreads() + register staging: 0 tripwire failures (r1-r8, r13).
__device__ __forceinline__ int swz_slot(int row, int c) {
    return row * 4 + (c ^ (row & 3) ^ ((row >> 2) & 3));
}

__device__ __forceinline__ uint4 cvt8(float4 a, float4 b) {
    f16x8 o;
    o[0] = (f16)a.x; o[1] = (f16)a.y; o[2] = (f16)a.z; o[3] = (f16)a.w;
    o[4] = (f16)b.x; o[5] = (f16)b.y; o[6] = (f16)b.z; o[7] = (f16)b.w;
    return __builtin_bit_cast(uint4, o);
}

__launch_bounds__(256)
__global__ void gemm_fused(const float* __restrict__ F, const f16* __restrict__ Wc,
                           const float* __restrict__ bias,
                           f16* __restrict__ Qb, f16* __restrict__ Kb, f16* __restrict__ Vb,
                           float* __restrict__ Out, int n) {
    __shared__ uint4 As4[512];   // 128 rows x 32 k (f16) = 8KB
    __shared__ uint4 Bs4[512];   // 128 rows x 32 k = 8KB
    int t = threadIdx.x;
    int lane = t & 63, w = t >> 6;
    int wm = w >> 1, wn = w & 1;
    long m0 = (long)blockIdx.y * 128;
    int n0 = blockIdx.x * 128;

    f32x4 acc[4][4];
    #pragma unroll
    for (int i = 0; i < 4; i++)
        #pragma unroll
        for (int j = 0; j < 4; j++)
            acc[i][j] = (f32x4){0.f, 0.f, 0.f, 0.f};

    int lrow = t >> 2, lc = t & 3;
    long row0 = m0 + lrow, row1 = m0 + 64 + lrow;
    const float4* Fg0 = (const float4*)(F + row0 * 256 + lc * 8);   // 8 f32 per thread
    const float4* Fg1 = (const float4*)(F + row1 * 256 + lc * 8);
    const uint4*  Bg0 = (const uint4*)(Wc + (long)(n0 + lrow) * 256 + lc * 8);
    const uint4*  Bg1 = (const uint4*)(Wc + (long)(n0 + 64 + lrow) * 256 + lc * 8);
    bool ok0 = row0 < n, ok1 = row1 < n;
    int ws0 = swz_slot(lrow, lc);
    int ws1 = swz_slot(lrow + 64, lc);
    int csw = (lane >> 4) ^ (lane & 3) ^ ((lane >> 2) & 3);
    int arow = wm * 64 + (lane & 15);
    int brow = wn * 64 + (lane & 15);

    float4 fa0 = {}, fb0 = {}, fa1 = {}, fb1 = {};
    if (ok0) { fa0 = Fg0[0]; fb0 = Fg0[1]; }
    if (ok1) { fa1 = Fg1[0]; fb1 = Fg1[1]; }
    uint4 rb0 = Bg0[0], rb1 = Bg1[0];
    for (int kt = 0; kt < 8; ++kt) {
        if (kt) __syncthreads();
        As4[ws0] = cvt8(fa0, fb0);
        As4[ws1] = cvt8(fa1, fb1);
        Bs4[ws0] = rb0;
        Bs4[ws1] = rb1;
        __syncthreads();
        if (kt < 7) {            // prefetch next K-slice (k step 32 f32 = 8 float4)
            if (ok0) { fa0 = Fg0[(kt + 1) * 8]; fb0 = Fg0[(kt + 1) * 8 + 1]; }
            if (ok1) { fa1 = Fg1[(kt + 1) * 8]; fb1 = Fg1[(kt + 1) * 8 + 1]; }
            rb0 = Bg0[(kt + 1) * 4];
            rb1 = Bg1[(kt + 1) * 4];
        }
        f16x8 af[4], bf[4];
        const f16x8* Ap = (const f16x8*)As4;
        const f16x8* Bp = (const f16x8*)Bs4;
        #pragma unroll
        for (int i = 0; i < 4; i++) af[i] = Ap[(arow + i * 16) * 4 + csw];
        #pragma unroll
        for (int j = 0; j < 4; j++) bf[j] = Bp[(brow + j * 16) * 4 + csw];
        #pragma unroll
        for (int i = 0; i < 4; i++)
            #pragma unroll
            for (int j = 0; j < 4; j++)
                acc[i][j] = __builtin_amdgcn_mfma_f32_16x16x32_f16(af[i], bf[j], acc[i][j], 0, 0, 0);
    }

    // epilogue: C row = (lane>>4)*4 + reg (M), col = lane&15 (N)  [m89-verified]
    #pragma unroll
    for (int i = 0; i < 4; i++) {
        long gmb = m0 + wm * 64 + i * 16 + (lane >> 4) * 4;
        #pragma unroll
        for (int j = 0; j < 4; j++) {
            int gn = n0 + wn * 64 + j * 16 + (lane & 15);
            float bv = bias[gn];
            #pragma unroll
            for (int r = 0; r < 4; r++) {
                long gm = gmb + r;
                if (gm >= n) continue;
                float v = acc[i][j][r] + bv;
                if (gn < 512)       Qb[gm * 512 + gn] = (f16)v;
                else if (gn < 1024) Kb[gm * 512 + (gn - 512)] = (f16)v;
                else if (gn < 1056) Vb[gm * 32 + (gn - 1024)] = (f16)v;
                else if (gn < 1312) Out[gm * 256 + (gn - 1056)] = v;
                // gn in [1312,1408): padding, no write
            }
        }
    }
}

// ---------------- f16x2 dot helper ----------------
__device__ __forceinline__ float fd2(unsigned a, unsigned b, float c) {
#if defined(__has_builtin)
#if __has_builtin(__builtin_amdgcn_fdot2)
    return __builtin_amdgcn_fdot2(__builtin_bit_cast(f16x2, a), __builtin_bit_cast(f16x2, b), c, false);
#else
    f16x2 x = __builtin_bit_cast(f16x2, a), y = __builtin_bit_cast(f16x2, b);
    return c + (float)x[0] * (float)y[0] + (float)x[1] * (float)y[1];
#endif
#else
    f16x2 x = __builtin_bit_cast(f16x2, a), y = __builtin_bit_cast(f16x2, b);
    return c + (float)x[0] * (float)y[0] + (float)x[1] * (float)y[1];
#endif
}

// ---------------- phase A v3: chunk-lane coalesced, head-phased scores -------------
// Thread = (edge, 16B-chunk j). Lanes j=0..7 of an edge read the 8 consecutive
// 16B chunks of the SAME 128B K line in ONE instruction -> hardware-coalesced
// into 1 transaction (r13's per-lane sequential 8x16B reads were 8 separate
// line transactions: 105M total, the measured ~351us rate wall). K transactions
// drop 8x to 13.2M. h = bid&7 keeps r11's per-XCD working-set win (FETCH 443MB).
// Partial dots reduced across the 8-lane group via 3 shfl_xor; lane j==0 stores
// (8 stores/wave at consecutive e -> 16B contiguous).
__launch_bounds__(256)
__global__ void edge_scores(const int* __restrict__ srcA, const int* __restrict__ dstA,
                            const f16* __restrict__ Qb, const f16* __restrict__ Kb,
                            f16* __restrict__ sE, int E, int Epad) {
    int bid = blockIdx.x;
    int h = bid & 7;                          // head = XCD (round-robin dispatch)
    int j = threadIdx.x & 7;                  // 16B chunk within the head's 128B line
    int e = (bid >> 3) * 32 + (threadIdx.x >> 3);
    if (e >= E) return;
    int s = srcA[e], d = dstA[e];             // 8 lanes same e -> same-address merge
    uint4 kv = *(const uint4*)(Kb + (size_t)d * 512 + h * 64 + j * 8);
    uint4 qv = *(const uint4*)(Qb + (size_t)s * 512 + h * 64 + j * 8);
    float a = 0.f;
    a = fd2(qv.x, kv.x, a);
    a = fd2(qv.y, kv.y, a);
    a = fd2(qv.z, kv.z, a);
    a = fd2(qv.w, kv.w, a);
    a += __shfl_xor(a, 1);                    // reduce across the 8-lane chunk group
    a += __shfl_xor(a, 2);
    a += __shfl_xor(a, 4);
    if (j == 0) sE[(size_t)h * Epad + e] = (f16)a;
}

// ---------------- phase B: row-parallel softmax + MFMA aggregation (r13-exact) -----
// Wave per row. Pass 1: per-head max. Pass 2: P = exp(s-m) -> LDS (XOR-swizzled);
// out[16h x 32d] = P @ Vgather via 4 MFMAs; denom l = P @ ones via 2 more MFMAs.
__launch_bounds__(256)
__global__ void edge_agg(const int* __restrict__ rs, const int* __restrict__ dstA,
                         const f16* __restrict__ sE, const f16* __restrict__ Vb,
                         float* __restrict__ Out, int n, int Epad) {
    __shared__ __align__(16) f16 P_lds[4][16][64];
    __shared__ int dS[4][64];
    int w = threadIdx.x >> 6, lane = threadIdx.x & 63;
    int row = blockIdx.x * 4 + w;
    if (row >= n) return;
    int e0 = rs[row], deg = rs[row + 1] - e0;
    {   // zero A-frag rows 8..15 (read by MFMA, results discarded; avoid NaN garbage)
        f16x8 z = {};
        *(f16x8*)&P_lds[w][8 + (lane >> 3)][(lane & 7) * 8] = z;
    }
    asm volatile("" ::: "memory");
    // pass 1: global per-head max
    float pm[8];
    #pragma unroll
    for (int h = 0; h < 8; h++) pm[h] = -1e30f;
    for (int base = 0; base < deg; base += 64) {
        bool act = lane < deg - base;
        int ee = e0 + base + (act ? lane : 0);
        #pragma unroll
        for (int h = 0; h < 8; h++) {
            float sv = act ? (float)sE[(size_t)h * Epad + ee] : -1e30f;
            pm[h] = fmaxf(pm[h], sv);
        }
    }
    float m[8];
    #pragma unroll
    for (int h = 0; h < 8; h++) {
        float v = pm[h];
        #pragma unroll
        for (int off = 1; off < 64; off <<= 1) v = fmaxf(v, __shfl_xor(v, off));
        m[h] = v;
    }
    // pass 2: P, V-MFMA, ones-MFMA (denominator)
    f32x4 acc0 = {}, acc1 = {}, accl = {};
    int ec0 = (lane >> 4) * 8, h_a = lane & 15, hsel = (lane >> 4) & 1;
    f16x8 ones;
    #pragma unroll
    for (int j = 0; j < 8; j++) ones[j] = (f16)1.f;
    for (int base = 0; base < deg; base += 64) {
        int nE = deg - base; if (nE > 64) nE = 64;
        bool act = lane < nE;
        int ee = e0 + base + (act ? lane : 0);
        int d = dstA[ee];
        dS[w][lane] = d;
        #pragma unroll
        for (int h = 0; h < 8; h++) {
            float sv = act ? (float)sE[(size_t)h * Epad + ee] : 0.f;
            float p = act ? __expf(sv - m[h]) : 0.f;
            P_lds[w][h][lane ^ (h << 3)] = (f16)p;
        }
        asm volatile("" ::: "memory");   // LDS writes ordered before the punned reads
        // A-frags: P[h][k], k = ks*32 + ec0 + j (XOR-decoded contiguous b128)
        f16x8 a0 = *(const f16x8*)&P_lds[w][h_a][(ec0)      ^ ((h_a & 7) << 3)];
        f16x8 a1 = *(const f16x8*)&P_lds[w][h_a][(32 + ec0) ^ ((h_a & 7) << 3)];
        // B-frags: V[e][dim], dim = nh*16 + (lane&15)
        f16x8 bf0a, bf0b, bf1a, bf1b;
        #pragma unroll
        for (int j = 0; j < 8; j++) {
            int dd0 = dS[w][ec0 + j];
            int dd1 = dS[w][32 + ec0 + j];
            const f16* vp0 = Vb + (size_t)dd0 * 32 + (lane & 15);
            const f16* vp1 = Vb + (size_t)dd1 * 32 + (lane & 15);
            bf0a[j] = vp0[0];  bf0b[j] = vp0[16];
            bf1a[j] = vp1[0];  bf1b[j] = vp1[16];
        }
        asm volatile("" ::: "memory");   // reads complete before next tile's writes
        acc0 = __builtin_amdgcn_mfma_f32_16x16x32_f16(a0, bf0a, acc0, 0, 0, 0);
        acc0 = __builtin_amdgcn_mfma_f32_16x16x32_f16(a1, bf1a, acc0, 0, 0, 0);
        acc1 = __builtin_amdgcn_mfma_f32_16x16x32_f16(a0, bf0b, acc1, 0, 0, 0);
        acc1 = __builtin_amdgcn_mfma_f32_16x16x32_f16(a1, bf1b, acc1, 0, 0, 0);
        accl = __builtin_amdgcn_mfma_f32_16x16x32_f16(a0, ones, accl, 0, 0, 0);
        accl = __builtin_amdgcn_mfma_f32_16x16x32_f16(a1, ones, accl, 0, 0, 0);
    }
    // epilogue: D row = hsel*4 + r = head, col = lane&15; out dim = h*32 + nh*16 + col
    if (lane < 32) {
        float* op = Out + (size_t)row * 256 + (lane & 15);
        #pragma unroll
        for (int r = 0; r < 4; r++) {
            int h = hsel * 4 + r;
            float inv = 1.f / accl[r];
            op[h * 32]      += acc0[r] * inv;
            op[h * 32 + 16] += acc1[r] * inv;
        }
    }
}

// ---------------- launch ----------------
extern "C" void kernel_launch(void* const* d_in, const int* in_sizes, int n_in,
                              void* d_out, int out_size, void* d_ws, size_t ws_size,
                              hipStream_t stream) {
    const float* F  = (const float*)d_in[0];
    const int*   ei = (const int*)d_in[1];
    const float* Wq = (const float*)d_in[2];
    const float* bq = (const float*)d_in[3];
    const float* Wk = (const float*)d_in[4];
    const float* bk = (const float*)d_in[5];
    const float* Ww = (const float*)d_in[6];
    const float* bw = (const float*)d_in[7];
    const float* Wb = (const float*)d_in[8];
    const float* bb = (const float*)d_in[9];
    int n = in_sizes[0] / 256;       // 50000
    int E = in_sizes[1] / 2;
    const int* srcA = ei;
    const int* dstA = ei + E;
    int n_pad = (n + 127) & ~127;
    int Epad = (E + 63) & ~63;

    // workspace carve-out (~133 MB)
    char* wp = (char*)d_ws;
    auto alloc = [&](size_t bytes) { void* p = wp; wp += (bytes + 255) & ~255ull; return p; };
    f16*   sE   = (f16*)alloc((size_t)Epad * 8 * 2);
    f16*   Wc   = (f16*)alloc((size_t)WC_PAD * 256 * 2);
    float* bias = (float*)alloc((size_t)WC_PAD * 4);
    f16*   Qb   = (f16*)alloc((size_t)n * 512 * 2);
    f16*   Kb   = (f16*)alloc((size_t)n * 512 * 2);
    f16*   Vb   = (f16*)alloc((size_t)n * 32 * 2);
    int*   rs   = (int*)alloc((size_t)(n + 1) * 4);
    float* Out  = (float*)d_out;

    prep_weights<<<WC_PAD, 256, 0, stream>>>(Wq, bq, Wk, bk, Ww, bw, Wc ? Wb : Wb, bb, Wc, bias);
    build_rows<<<(E + 255) / 256, 256, 0, stream>>>(srcA, E, n, rs);
    dim3 g(WC_PAD / 128, n_pad / 128);   // N fastest: A-panel L2-reuse, B L2-resident
    gemm_fused<<<g, 256, 0, stream>>>(F, Wc, bias, Qb, Kb, Vb, Out, n);
    int wgph = (E + 31) / 32;            // 32 edges per block per head
    edge_scores<<<8 * wgph, 256, 0, stream>>>(srcA, dstA, Qb, Kb, sE, E, Epad);
    edge_agg<<<(n + 3) / 4, 256, 0, stream>>>(rs, dstA, sE, Vb, Out, n, Epad);
}

// Round 15
// 456.046 us; speedup vs baseline: 1.2385x; 1.0716x over previous
//
#include <hip/hip_runtime.h>
#include <hip/hip_fp16.h>

typedef _Float16 f16;
typedef _Float16 f16x2 __attribute__((ext_vector_type(2)));
typedef _Float16 f16x8 __attribute__((ext_vector_type(8)));
typedef float f32x4 __attribute__((ext_vector_type(4)));

// Combined projection: rows 0..511 = Wq (8 heads x 64), 512..1023 = Wk,
// 1024..1055 = Ww (V), 1056..1311 = Wb (output). Padded to 1408 rows (128-mult).
#define WC_ROWS 1312
#define WC_PAD 1408

// ---------------- prep: combined weight matrix (f16) + bias (f32) ----------------
__global__ void prep_weights(const float* __restrict__ Wq, const float* __restrict__ bq,
                             const float* __restrict__ Wk, const float* __restrict__ bk,
                             const float* __restrict__ Ww, const float* __restrict__ bw,
                             const float* __restrict__ Wb, const float* __restrict__ bb,
                             f16* __restrict__ Wc, float* __restrict__ bias) {
    int id = blockIdx.x * 256 + threadIdx.x;   // WC_PAD*256 threads
    int j = id >> 8, k = id & 255;
    if (j >= WC_PAD) return;
    float v;
    if (j < 512)       v = Wq[j*256 + k];          // Wq flat [8,64,256]: row h*64+d == j
    else if (j < 1024) v = Wk[(j-512)*256 + k];
    else if (j < 1056) v = Ww[(j-1024)*256 + k];
    else if (j < 1312) v = Wb[(j-1056)*256 + k];
    else               v = 0.f;
    Wc[j*256 + k] = (f16)v;
    if (k == 0) {
        float b;
        if (j < 512)       b = bq[j];
        else if (j < 1024) b = bk[j-512];
        else if (j < 1056) b = bw[j-1024];
        else if (j < 1312) b = bb[j-1056];
        else               b = 0.f;
        bias[j] = b;
    }
}

// ---------------- prep: CSR row starts (edges sorted by src; every row non-empty) --
__global__ void build_rows(const int* __restrict__ src, int E, int n, int* __restrict__ rs) {
    int e = blockIdx.x * 256 + threadIdx.x;
    if (e == 0) rs[n] = E;
    if (e < E) {
        if (e == 0 || src[e] != src[e-1]) rs[src[e]] = e;
    }
}

// ---------------- fused projection GEMM (r6-proven reg-staged version) -------------
// __syncthreads() + register staging: 0 tripwire failures (r1-r8, r13, r14).
__device__ __forceinline__ int swz_slot(int row, int c) {
    return row * 4 + (c ^ (row & 3) ^ ((row >> 2) & 3));
}

__device__ __forceinline__ uint4 cvt8(float4 a, float4 b) {
    f16x8 o;
    o[0] = (f16)a.x; o[1] = (f16)a.y; o[2] = (f16)a.z; o[3] = (f16)a.w;
    o[4] = (f16)b.x; o[5] = (f16)b.y; o[6] = (f16)b.z; o[7] = (f16)b.w;
    return __builtin_bit_cast(uint4, o);
}

__launch_bounds__(256)
__global__ void gemm_fused(const float* __restrict__ F, const f16* __restrict__ Wc,
                           const float* __restrict__ bias,
                           f16* __restrict__ Qb, f16* __restrict__ Kb, f16* __restrict__ Vb,
                           float* __restrict__ Out, int n) {
    __shared__ uint4 As4[512];   // 128 rows x 32 k (f16) = 8KB
    __shared__ uint4 Bs4[512];   // 128 rows x 32 k = 8KB
    int t = threadIdx.x;
    int lane = t & 63, w = t >> 6;
    int wm = w >> 1, wn = w & 1;
    long m0 = (long)blockIdx.y * 128;
    int n0 = blockIdx.x * 128;

    f32x4 acc[4][4];
    #pragma unroll
    for (int i = 0; i < 4; i++)
        #pragma unroll
        for (int j = 0; j < 4; j++)
            acc[i][j] = (f32x4){0.f, 0.f, 0.f, 0.f};

    int lrow = t >> 2, lc = t & 3;
    long row0 = m0 + lrow, row1 = m0 + 64 + lrow;
    const float4* Fg0 = (const float4*)(F + row0 * 256 + lc * 8);   // 8 f32 per thread
    const float4* Fg1 = (const float4*)(F + row1 * 256 + lc * 8);
    const uint4*  Bg0 = (const uint4*)(Wc + (long)(n0 + lrow) * 256 + lc * 8);
    const uint4*  Bg1 = (const uint4*)(Wc + (long)(n0 + 64 + lrow) * 256 + lc * 8);
    bool ok0 = row0 < n, ok1 = row1 < n;
    int ws0 = swz_slot(lrow, lc);
    int ws1 = swz_slot(lrow + 64, lc);
    int csw = (lane >> 4) ^ (lane & 3) ^ ((lane >> 2) & 3);
    int arow = wm * 64 + (lane & 15);
    int brow = wn * 64 + (lane & 15);

    float4 fa0 = {}, fb0 = {}, fa1 = {}, fb1 = {};
    if (ok0) { fa0 = Fg0[0]; fb0 = Fg0[1]; }
    if (ok1) { fa1 = Fg1[0]; fb1 = Fg1[1]; }
    uint4 rb0 = Bg0[0], rb1 = Bg1[0];
    for (int kt = 0; kt < 8; ++kt) {
        if (kt) __syncthreads();
        As4[ws0] = cvt8(fa0, fb0);
        As4[ws1] = cvt8(fa1, fb1);
        Bs4[ws0] = rb0;
        Bs4[ws1] = rb1;
        __syncthreads();
        if (kt < 7) {            // prefetch next K-slice (k step 32 f32 = 8 float4)
            if (ok0) { fa0 = Fg0[(kt + 1) * 8]; fb0 = Fg0[(kt + 1) * 8 + 1]; }
            if (ok1) { fa1 = Fg1[(kt + 1) * 8]; fb1 = Fg1[(kt + 1) * 8 + 1]; }
            rb0 = Bg0[(kt + 1) * 4];
            rb1 = Bg1[(kt + 1) * 4];
        }
        f16x8 af[4], bf[4];
        const f16x8* Ap = (const f16x8*)As4;
        const f16x8* Bp = (const f16x8*)Bs4;
        #pragma unroll
        for (int i = 0; i < 4; i++) af[i] = Ap[(arow + i * 16) * 4 + csw];
        #pragma unroll
        for (int j = 0; j < 4; j++) bf[j] = Bp[(brow + j * 16) * 4 + csw];
        #pragma unroll
        for (int i = 0; i < 4; i++)
            #pragma unroll
            for (int j = 0; j < 4; j++)
                acc[i][j] = __builtin_amdgcn_mfma_f32_16x16x32_f16(af[i], bf[j], acc[i][j], 0, 0, 0);
    }

    // epilogue: C row = (lane>>4)*4 + reg (M), col = lane&15 (N)  [m89-verified]
    #pragma unroll
    for (int i = 0; i < 4; i++) {
        long gmb = m0 + wm * 64 + i * 16 + (lane >> 4) * 4;
        #pragma unroll
        for (int j = 0; j < 4; j++) {
            int gn = n0 + wn * 64 + j * 16 + (lane & 15);
            float bv = bias[gn];
            #pragma unroll
            for (int r = 0; r < 4; r++) {
                long gm = gmb + r;
                if (gm >= n) continue;
                float v = acc[i][j][r] + bv;
                if (gn < 512)       Qb[gm * 512 + gn] = (f16)v;
                else if (gn < 1024) Kb[gm * 512 + (gn - 512)] = (f16)v;
                else if (gn < 1056) Vb[gm * 32 + (gn - 1024)] = (f16)v;
                else if (gn < 1312) Out[gm * 256 + (gn - 1056)] = v;
                // gn in [1312,1408): padding, no write
            }
        }
    }
}

// ---------------- f16x2 dot helper ----------------
__device__ __forceinline__ float fd2(unsigned a, unsigned b, float c) {
#if defined(__has_builtin)
#if __has_builtin(__builtin_amdgcn_fdot2)
    return __builtin_amdgcn_fdot2(__builtin_bit_cast(f16x2, a), __builtin_bit_cast(f16x2, b), c, false);
#else
    f16x2 x = __builtin_bit_cast(f16x2, a), y = __builtin_bit_cast(f16x2, b);
    return c + (float)x[0] * (float)y[0] + (float)x[1] * (float)y[1];
#endif
#else
    f16x2 x = __builtin_bit_cast(f16x2, a), y = __builtin_bit_cast(f16x2, b);
    return c + (float)x[0] * (float)y[0] + (float)x[1] * (float)y[1];
#endif
}

// ---------------- phase A v4: chunk-lane coalesced, 4 edges/thread -----------------
// r14 proved line-coalescing (transactions /8, dur 351->285us) but left the kernel
// half issue-bound (VALUBusy 45%, 13.2M tiny waves). v4 amortizes: each thread
// handles 4 edges; all 4 K-line loads + 4 Q loads issue back-to-back (8 memory
// ops in flight -> real MLP), then 16 fd2. Wave count /4. Lanes j=0..7 of a group
// still read the 8 consecutive 16B chunks of one 128B K line in ONE instruction.
// h = bid&7 keeps the per-XCD head working-set win (FETCH ~441MB).
__launch_bounds__(256)
__global__ void edge_scores(const int* __restrict__ srcA, const int* __restrict__ dstA,
                            const f16* __restrict__ Qb, const f16* __restrict__ Kb,
                            f16* __restrict__ sE, int E, int Epad) {
    int bid = blockIdx.x;
    int h = bid & 7;                          // head = XCD (round-robin dispatch)
    int j = threadIdx.x & 7;                  // 16B chunk within the head's 128B line
    int g = threadIdx.x >> 3;                 // edge group 0..31
    int e0 = (bid >> 3) * 128 + g;            // edges e0 + 32*u, u=0..3
    int s[4], d[4];
    #pragma unroll
    for (int u = 0; u < 4; u++) {
        int e = e0 + 32 * u;
        bool ok = e < E;
        s[u] = ok ? srcA[e] : 0;
        d[u] = ok ? dstA[e] : 0;
    }
    uint4 kv[4], qv[4];
    #pragma unroll
    for (int u = 0; u < 4; u++)               // 4 gather lines issued back-to-back
        kv[u] = *(const uint4*)(Kb + (size_t)d[u] * 512 + h * 64 + j * 8);
    #pragma unroll
    for (int u = 0; u < 4; u++)               // 4 Q chunks (L1/L2-hot)
        qv[u] = *(const uint4*)(Qb + (size_t)s[u] * 512 + h * 64 + j * 8);
    #pragma unroll
    for (int u = 0; u < 4; u++) {
        float a = 0.f;
        a = fd2(qv[u].x, kv[u].x, a);
        a = fd2(qv[u].y, kv[u].y, a);
        a = fd2(qv[u].z, kv[u].z, a);
        a = fd2(qv[u].w, kv[u].w, a);
        a += __shfl_xor(a, 1);                // reduce across the 8-lane chunk group
        a += __shfl_xor(a, 2);
        a += __shfl_xor(a, 4);
        int e = e0 + 32 * u;
        if (j == 0 && e < E)                  // 8 consecutive e per wave -> 16B store
            sE[(size_t)h * Epad + e] = (f16)a;
    }
}

// ---------------- phase B: row-parallel softmax + MFMA aggregation (r13-exact) -----
// Wave per row. Pass 1: per-head max. Pass 2: P = exp(s-m) -> LDS (XOR-swizzled);
// out[16h x 32d] = P @ Vgather via 4 MFMAs; denom l = P @ ones via 2 more MFMAs.
__launch_bounds__(256)
__global__ void edge_agg(const int* __restrict__ rs, const int* __restrict__ dstA,
                         const f16* __restrict__ sE, const f16* __restrict__ Vb,
                         float* __restrict__ Out, int n, int Epad) {
    __shared__ __align__(16) f16 P_lds[4][16][64];
    __shared__ int dS[4][64];
    int w = threadIdx.x >> 6, lane = threadIdx.x & 63;
    int row = blockIdx.x * 4 + w;
    if (row >= n) return;
    int e0 = rs[row], deg = rs[row + 1] - e0;
    {   // zero A-frag rows 8..15 (read by MFMA, results discarded; avoid NaN garbage)
        f16x8 z = {};
        *(f16x8*)&P_lds[w][8 + (lane >> 3)][(lane & 7) * 8] = z;
    }
    asm volatile("" ::: "memory");
    // pass 1: global per-head max
    float pm[8];
    #pragma unroll
    for (int h = 0; h < 8; h++) pm[h] = -1e30f;
    for (int base = 0; base < deg; base += 64) {
        bool act = lane < deg - base;
        int ee = e0 + base + (act ? lane : 0);
        #pragma unroll
        for (int h = 0; h < 8; h++) {
            float sv = act ? (float)sE[(size_t)h * Epad + ee] : -1e30f;
            pm[h] = fmaxf(pm[h], sv);
        }
    }
    float m[8];
    #pragma unroll
    for (int h = 0; h < 8; h++) {
        float v = pm[h];
        #pragma unroll
        for (int off = 1; off < 64; off <<= 1) v = fmaxf(v, __shfl_xor(v, off));
        m[h] = v;
    }
    // pass 2: P, V-MFMA, ones-MFMA (denominator)
    f32x4 acc0 = {}, acc1 = {}, accl = {};
    int ec0 = (lane >> 4) * 8, h_a = lane & 15, hsel = (lane >> 4) & 1;
    f16x8 ones;
    #pragma unroll
    for (int j = 0; j < 8; j++) ones[j] = (f16)1.f;
    for (int base = 0; base < deg; base += 64) {
        int nE = deg - base; if (nE > 64) nE = 64;
        bool act = lane < nE;
        int ee = e0 + base + (act ? lane : 0);
        int d = dstA[ee];
        dS[w][lane] = d;
        #pragma unroll
        for (int h = 0; h < 8; h++) {
            float sv = act ? (float)sE[(size_t)h * Epad + ee] : 0.f;
            float p = act ? __expf(sv - m[h]) : 0.f;
            P_lds[w][h][lane ^ (h << 3)] = (f16)p;
        }
        asm volatile("" ::: "memory");   // LDS writes ordered before the punned reads
        // A-frags: P[h][k], k = ks*32 + ec0 + j (XOR-decoded contiguous b128)
        f16x8 a0 = *(const f16x8*)&P_lds[w][h_a][(ec0)      ^ ((h_a & 7) << 3)];
        f16x8 a1 = *(const f16x8*)&P_lds[w][h_a][(32 + ec0) ^ ((h_a & 7) << 3)];
        // B-frags: V[e][dim], dim = nh*16 + (lane&15)
        f16x8 bf0a, bf0b, bf1a, bf1b;
        #pragma unroll
        for (int j = 0; j < 8; j++) {
            int dd0 = dS[w][ec0 + j];
            int dd1 = dS[w][32 + ec0 + j];
            const f16* vp0 = Vb + (size_t)dd0 * 32 + (lane & 15);
            const f16* vp1 = Vb + (size_t)dd1 * 32 + (lane & 15);
            bf0a[j] = vp0[0];  bf0b[j] = vp0[16];
            bf1a[j] = vp1[0];  bf1b[j] = vp1[16];
        }
        asm volatile("" ::: "memory");   // reads complete before next tile's writes
        acc0 = __builtin_amdgcn_mfma_f32_16x16x32_f16(a0, bf0a, acc0, 0, 0, 0);
        acc0 = __builtin_amdgcn_mfma_f32_16x16x32_f16(a1, bf1a, acc0, 0, 0, 0);
        acc1 = __builtin_amdgcn_mfma_f32_16x16x32_f16(a0, bf0b, acc1, 0, 0, 0);
        acc1 = __builtin_amdgcn_mfma_f32_16x16x32_f16(a1, bf1b, acc1, 0, 0, 0);
        accl = __builtin_amdgcn_mfma_f32_16x16x32_f16(a0, ones, accl, 0, 0, 0);
        accl = __builtin_amdgcn_mfma_f32_16x16x32_f16(a1, ones, accl, 0, 0, 0);
    }
    // epilogue: D row = hsel*4 + r = head, col = lane&15; out dim = h*32 + nh*16 + col
    if (lane < 32) {
        float* op = Out + (size_t)row * 256 + (lane & 15);
        #pragma unroll
        for (int r = 0; r < 4; r++) {
            int h = hsel * 4 + r;
            float inv = 1.f / accl[r];
            op[h * 32]      += acc0[r] * inv;
            op[h * 32 + 16] += acc1[r] * inv;
        }
    }
}

// ---------------- launch ----------------
extern "C" void kernel_launch(void* const* d_in, const int* in_sizes, int n_in,
                              void* d_out, int out_size, void* d_ws, size_t ws_size,
                              hipStream_t stream) {
    const float* F  = (const float*)d_in[0];
    const int*   ei = (const int*)d_in[1];
    const float* Wq = (const float*)d_in[2];
    const float* bq = (const float*)d_in[3];
    const float* Wk = (const float*)d_in[4];
    const float* bk = (const float*)d_in[5];
    const float* Ww = (const float*)d_in[6];
    const float* bw = (const float*)d_in[7];
    const float* Wb = (const float*)d_in[8];
    const float* bb = (const float*)d_in[9];
    int n = in_sizes[0] / 256;       // 50000
    int E = in_sizes[1] / 2;
    const int* srcA = ei;
    const int* dstA = ei + E;
    int n_pad = (n + 127) & ~127;
    int Epad = (E + 63) & ~63;

    // workspace carve-out (~133 MB)
    char* wp = (char*)d_ws;
    auto alloc = [&](size_t bytes) { void* p = wp; wp += (bytes + 255) & ~255ull; return p; };
    f16*   sE   = (f16*)alloc((size_t)Epad * 8 * 2);
    f16*   Wc   = (f16*)alloc((size_t)WC_PAD * 256 * 2);
    float* bias = (float*)alloc((size_t)WC_PAD * 4);
    f16*   Qb   = (f16*)alloc((size_t)n * 512 * 2);
    f16*   Kb   = (f16*)alloc((size_t)n * 512 * 2);
    f16*   Vb   = (f16*)alloc((size_t)n * 32 * 2);
    int*   rs   = (int*)alloc((size_t)(n + 1) * 4);
    float* Out  = (float*)d_out;

    prep_weights<<<WC_PAD, 256, 0, stream>>>(Wq, bq, Wk, bk, Ww, bw, Wb, bb, Wc, bias);
    build_rows<<<(E + 255) / 256, 256, 0, stream>>>(srcA, E, n, rs);
    dim3 g(WC_PAD / 128, n_pad / 128);   // N fastest: A-panel L2-reuse, B L2-resident
    gemm_fused<<<g, 256, 0, stream>>>(F, Wc, bias, Qb, Kb, Vb, Out, n);
    int wgph = (E + 127) / 128;          // 128 edges per block per head
    edge_scores<<<8 * wgph, 256, 0, stream>>>(srcA, dstA, Qb, Kb, sE, E, Epad);
    edge_agg<<<(n + 3) / 4, 256, 0, stream>>>(rs, dstA, sE, Vb, Out, n, Epad);
}

// Round 16
// 449.538 us; speedup vs baseline: 1.2564x; 1.0145x over previous
//
#include <hip/hip_runtime.h>
#include <hip/hip_fp16.h>

typedef _Float16 f16;
typedef _Float16 f16x2 __attribute__((ext_vector_type(2)));
typedef _Float16 f16x8 __attribute__((ext_vector_type(8)));
typedef float f32x4 __attribute__((ext_vector_type(4)));

// Combined projection: rows 0..511 = Wq (8 heads x 64), 512..1023 = Wk,
// 1024..1055 = Ww (V), 1056..1311 = Wb (output). Padded to 1408 rows (128-mult).
#define WC_ROWS 1312
#define WC_PAD 1408

// ---------------- prep: combined weight matrix (f16) + bias (f32) ----------------
__global__ void prep_weights(const float* __restrict__ Wq, const float* __restrict__ bq,
                             const float* __restrict__ Wk, const float* __restrict__ bk,
                             const float* __restrict__ Ww, const float* __restrict__ bw,
                             const float* __restrict__ Wb, const float* __restrict__ bb,
                             f16* __restrict__ Wc, float* __restrict__ bias) {
    int id = blockIdx.x * 256 + threadIdx.x;   // WC_PAD*256 threads
    int j = id >> 8, k = id & 255;
    if (j >= WC_PAD) return;
    float v;
    if (j < 512)       v = Wq[j*256 + k];          // Wq flat [8,64,256]: row h*64+d == j
    else if (j < 1024) v = Wk[(j-512)*256 + k];
    else if (j < 1056) v = Ww[(j-1024)*256 + k];
    else if (j < 1312) v = Wb[(j-1056)*256 + k];
    else               v = 0.f;
    Wc[j*256 + k] = (f16)v;
    if (k == 0) {
        float b;
        if (j < 512)       b = bq[j];
        else if (j < 1024) b = bk[j-512];
        else if (j < 1056) b = bw[j-1024];
        else if (j < 1312) b = bb[j-1056];
        else               b = 0.f;
        bias[j] = b;
    }
}

// ---------------- prep: CSR row starts (edges sorted by src; every row non-empty) --
__global__ void build_rows(const int* __restrict__ src, int E, int n, int* __restrict__ rs) {
    int e = blockIdx.x * 256 + threadIdx.x;
    if (e == 0) rs[n] = E;
    if (e < E) {
        if (e == 0 || src[e] != src[e-1]) rs[src[e]] = e;
    }
}

// ---------------- fused projection GEMM (r6-proven reg-staged version) -------------
// __syncthreads() + register staging: 0 tripwire failures (r1-r8, r13-r15).
// NOT reverting to global_load_lds/raw-s_barrier: s_barrier is not an LLVM memory
// fence, so next-tile stages can hoist above it -> cross-wave LDS race (r10/r12).
__device__ __forceinline__ int swz_slot(int row, int c) {
    return row * 4 + (c ^ (row & 3) ^ ((row >> 2) & 3));
}

__device__ __forceinline__ uint4 cvt8(float4 a, float4 b) {
    f16x8 o;
    o[0] = (f16)a.x; o[1] = (f16)a.y; o[2] = (f16)a.z; o[3] = (f16)a.w;
    o[4] = (f16)b.x; o[5] = (f16)b.y; o[6] = (f16)b.z; o[7] = (f16)b.w;
    return __builtin_bit_cast(uint4, o);
}

__launch_bounds__(256)
__global__ void gemm_fused(const float* __restrict__ F, const f16* __restrict__ Wc,
                           const float* __restrict__ bias,
                           f16* __restrict__ Qb, f16* __restrict__ Kb, f16* __restrict__ Vb,
                           float* __restrict__ Out, int n) {
    __shared__ uint4 As4[512];   // 128 rows x 32 k (f16) = 8KB
    __shared__ uint4 Bs4[512];   // 128 rows x 32 k = 8KB
    int t = threadIdx.x;
    int lane = t & 63, w = t >> 6;
    int wm = w >> 1, wn = w & 1;
    long m0 = (long)blockIdx.y * 128;
    int n0 = blockIdx.x * 128;

    f32x4 acc[4][4];
    #pragma unroll
    for (int i = 0; i < 4; i++)
        #pragma unroll
        for (int j = 0; j < 4; j++)
            acc[i][j] = (f32x4){0.f, 0.f, 0.f, 0.f};

    int lrow = t >> 2, lc = t & 3;
    long row0 = m0 + lrow, row1 = m0 + 64 + lrow;
    const float4* Fg0 = (const float4*)(F + row0 * 256 + lc * 8);   // 8 f32 per thread
    const float4* Fg1 = (const float4*)(F + row1 * 256 + lc * 8);
    const uint4*  Bg0 = (const uint4*)(Wc + (long)(n0 + lrow) * 256 + lc * 8);
    const uint4*  Bg1 = (const uint4*)(Wc + (long)(n0 + 64 + lrow) * 256 + lc * 8);
    bool ok0 = row0 < n, ok1 = row1 < n;
    int ws0 = swz_slot(lrow, lc);
    int ws1 = swz_slot(lrow + 64, lc);
    int csw = (lane >> 4) ^ (lane & 3) ^ ((lane >> 2) & 3);
    int arow = wm * 64 + (lane & 15);
    int brow = wn * 64 + (lane & 15);

    float4 fa0 = {}, fb0 = {}, fa1 = {}, fb1 = {};
    if (ok0) { fa0 = Fg0[0]; fb0 = Fg0[1]; }
    if (ok1) { fa1 = Fg1[0]; fb1 = Fg1[1]; }
    uint4 rb0 = Bg0[0], rb1 = Bg1[0];
    for (int kt = 0; kt < 8; ++kt) {
        if (kt) __syncthreads();
        As4[ws0] = cvt8(fa0, fb0);
        As4[ws1] = cvt8(fa1, fb1);
        Bs4[ws0] = rb0;
        Bs4[ws1] = rb1;
        __syncthreads();
        if (kt < 7) {            // prefetch next K-slice (k step 32 f32 = 8 float4)
            if (ok0) { fa0 = Fg0[(kt + 1) * 8]; fb0 = Fg0[(kt + 1) * 8 + 1]; }
            if (ok1) { fa1 = Fg1[(kt + 1) * 8]; fb1 = Fg1[(kt + 1) * 8 + 1]; }
            rb0 = Bg0[(kt + 1) * 4];
            rb1 = Bg1[(kt + 1) * 4];
        }
        f16x8 af[4], bf[4];
        const f16x8* Ap = (const f16x8*)As4;
        const f16x8* Bp = (const f16x8*)Bs4;
        #pragma unroll
        for (int i = 0; i < 4; i++) af[i] = Ap[(arow + i * 16) * 4 + csw];
        #pragma unroll
        for (int j = 0; j < 4; j++) bf[j] = Bp[(brow + j * 16) * 4 + csw];
        #pragma unroll
        for (int i = 0; i < 4; i++)
            #pragma unroll
            for (int j = 0; j < 4; j++)
                acc[i][j] = __builtin_amdgcn_mfma_f32_16x16x32_f16(af[i], bf[j], acc[i][j], 0, 0, 0);
    }

    // epilogue: C row = (lane>>4)*4 + reg (M), col = lane&15 (N)  [m89-verified]
    #pragma unroll
    for (int i = 0; i < 4; i++) {
        long gmb = m0 + wm * 64 + i * 16 + (lane >> 4) * 4;
        #pragma unroll
        for (int j = 0; j < 4; j++) {
            int gn = n0 + wn * 64 + j * 16 + (lane & 15);
            float bv = bias[gn];
            #pragma unroll
            for (int r = 0; r < 4; r++) {
                long gm = gmb + r;
                if (gm >= n) continue;
                float v = acc[i][j][r] + bv;
                if (gn < 512)       Qb[gm * 512 + gn] = (f16)v;
                else if (gn < 1024) Kb[gm * 512 + (gn - 512)] = (f16)v;
                else if (gn < 1056) Vb[gm * 32 + (gn - 1024)] = (f16)v;
                else if (gn < 1312) Out[gm * 256 + (gn - 1056)] = v;
                // gn in [1312,1408): padding, no write
            }
        }
    }
}

// ---------------- f16x2 dot helper ----------------
__device__ __forceinline__ float fd2(unsigned a, unsigned b, float c) {
#if defined(__has_builtin)
#if __has_builtin(__builtin_amdgcn_fdot2)
    return __builtin_amdgcn_fdot2(__builtin_bit_cast(f16x2, a), __builtin_bit_cast(f16x2, b), c, false);
#else
    f16x2 x = __builtin_bit_cast(f16x2, a), y = __builtin_bit_cast(f16x2, b);
    return c + (float)x[0] * (float)y[0] + (float)x[1] * (float)y[1];
#endif
#else
    f16x2 x = __builtin_bit_cast(f16x2, a), y = __builtin_bit_cast(f16x2, b);
    return c + (float)x[0] * (float)y[0] + (float)x[1] * (float)y[1];
#endif
}

// ---------------- phase A v5: chunk-lane coalesced, 4 edges/thread, packed reduce --
// Structure of r15 (lanes j=0..7 read one 128B K line in ONE instruction; 4 edges
// per thread; h = bid&7 head-phasing). v5 packs the 4 per-edge partial dots into
// 2x f16x2 and reduces with 3 packed shuffle+v_pk_add_f16 rounds (6 shfl + 6 add
// vs 12 + 12) — r15 was still ~30% VALU-busy. f16 partial rounding adds ~1e-3 to
// scores (output delta << threshold margin).
__launch_bounds__(256)
__global__ void edge_scores(const int* __restrict__ srcA, const int* __restrict__ dstA,
                            const f16* __restrict__ Qb, const f16* __restrict__ Kb,
                            f16* __restrict__ sE, int E, int Epad) {
    int bid = blockIdx.x;
    int h = bid & 7;                          // head = XCD (round-robin dispatch)
    int j = threadIdx.x & 7;                  // 16B chunk within the head's 128B line
    int g = threadIdx.x >> 3;                 // edge group 0..31
    int e0 = (bid >> 3) * 128 + g;            // edges e0 + 32*u, u=0..3
    int s[4], d[4];
    #pragma unroll
    for (int u = 0; u < 4; u++) {
        int e = e0 + 32 * u;
        bool ok = e < E;
        s[u] = ok ? srcA[e] : 0;
        d[u] = ok ? dstA[e] : 0;
    }
    uint4 kv[4], qv[4];
    #pragma unroll
    for (int u = 0; u < 4; u++)               // 4 gather lines issued back-to-back
        kv[u] = *(const uint4*)(Kb + (size_t)d[u] * 512 + h * 64 + j * 8);
    #pragma unroll
    for (int u = 0; u < 4; u++)               // 4 Q chunks (L1/L2-hot)
        qv[u] = *(const uint4*)(Qb + (size_t)s[u] * 512 + h * 64 + j * 8);
    float aa[4];
    #pragma unroll
    for (int u = 0; u < 4; u++) {
        float a = 0.f;
        a = fd2(qv[u].x, kv[u].x, a);
        a = fd2(qv[u].y, kv[u].y, a);
        a = fd2(qv[u].z, kv[u].z, a);
        a = fd2(qv[u].w, kv[u].w, a);
        aa[u] = a;
    }
    // packed 8-lane-group reduction: 2 regs carry 4 edges' partials
    f16x2 p01, p23;
    p01[0] = (f16)aa[0]; p01[1] = (f16)aa[1];
    p23[0] = (f16)aa[2]; p23[1] = (f16)aa[3];
    unsigned u01 = __builtin_bit_cast(unsigned, p01);
    unsigned u23 = __builtin_bit_cast(unsigned, p23);
    #pragma unroll
    for (int off = 1; off < 8; off <<= 1) {
        unsigned v01 = __shfl_xor(u01, off);
        unsigned v23 = __shfl_xor(u23, off);
        f16x2 r01 = __builtin_bit_cast(f16x2, u01) + __builtin_bit_cast(f16x2, v01);
        f16x2 r23 = __builtin_bit_cast(f16x2, u23) + __builtin_bit_cast(f16x2, v23);
        u01 = __builtin_bit_cast(unsigned, r01);
        u23 = __builtin_bit_cast(unsigned, r23);
    }
    if (j == 0) {
        f16x2 r01 = __builtin_bit_cast(f16x2, u01);
        f16x2 r23 = __builtin_bit_cast(f16x2, u23);
        size_t bo = (size_t)h * Epad;
        if (e0 < E)      sE[bo + e0]      = r01[0];
        if (e0+32 < E)   sE[bo + e0+32]   = r01[1];
        if (e0+64 < E)   sE[bo + e0+64]   = r23[0];
        if (e0+96 < E)   sE[bo + e0+96]   = r23[1];
    }
}

// ---------------- phase B v2: SINGLE-PASS online softmax + MFMA aggregation --------
// Per 64-edge tile: per-head tile-max (butterfly) -> nm = max(m, tmax); rescale
// the three accumulators by exp(m-nm) (first tile: exp(-inf)=0 on zero accs);
// P = exp(s-nm) -> LDS (XOR-swizzled); out += P @ Vgather (4 MFMAs);
// denom += P @ ones (2 MFMAs). Deletes the whole pass-1 loop (sE+dstA re-read
// and its latency chain). Retry of the r10 variant: the r10/r12 tripwire
// failures correlate with gemm-v3's raw-s_barrier race (now removed, 3/3 clean
// rounds since); this is the controlled experiment that convicts or exonerates
// the online-softmax structure itself. All state is wave-private register math.
__launch_bounds__(256)
__global__ void edge_agg(const int* __restrict__ rs, const int* __restrict__ dstA,
                         const f16* __restrict__ sE, const f16* __restrict__ Vb,
                         float* __restrict__ Out, int n, int Epad) {
    __shared__ __align__(16) f16 P_lds[4][16][64];
    __shared__ int dS[4][64];
    int w = threadIdx.x >> 6, lane = threadIdx.x & 63;
    int row = blockIdx.x * 4 + w;
    if (row >= n) return;
    int e0 = rs[row], deg = rs[row + 1] - e0;
    {   // zero A-frag rows 8..15 (read by MFMA, results discarded; avoid NaN garbage)
        f16x8 z = {};
        *(f16x8*)&P_lds[w][8 + (lane >> 3)][(lane & 7) * 8] = z;
    }
    asm volatile("" ::: "memory");
    float m[8];
    #pragma unroll
    for (int h = 0; h < 8; h++) m[h] = -1e30f;
    f32x4 acc0 = {}, acc1 = {}, accl = {};
    int ec0 = (lane >> 4) * 8, h_a = lane & 15, hsel = (lane >> 4) & 1;
    f16x8 ones;
    #pragma unroll
    for (int j = 0; j < 8; j++) ones[j] = (f16)1.f;

    for (int base = 0; base < deg; base += 64) {
        int nE = deg - base; if (nE > 64) nE = 64;
        bool act = lane < nE;
        int ee = e0 + base + (act ? lane : 0);
        dS[w][lane] = dstA[ee];
        float sc[8];
        #pragma unroll
        for (int h = 0; h < 8; h++) {
            float sv = act ? (float)sE[(size_t)h * Epad + ee] : -1e30f;
            float tv = sv;
            #pragma unroll
            for (int off = 1; off < 64; off <<= 1) tv = fmaxf(tv, __shfl_xor(tv, off));
            float nm = fmaxf(m[h], tv);
            sc[h] = __expf(m[h] - nm);
            float p = act ? __expf(sv - nm) : 0.f;
            P_lds[w][h][lane ^ (h << 3)] = (f16)p;
            m[h] = nm;
        }
        #pragma unroll
        for (int r = 0; r < 4; r++) {   // rescale accs (head = hsel*4 + r)
            float f = hsel ? sc[r + 4] : sc[r];
            acc0[r] *= f;
            acc1[r] *= f;
            accl[r] *= f;
        }
        asm volatile("" ::: "memory");   // LDS writes ordered before the punned reads
        // A-frags: P[h][k], k = ks*32 + ec0 + j (XOR-decoded contiguous b128)
        f16x8 a0 = *(const f16x8*)&P_lds[w][h_a][(ec0)      ^ ((h_a & 7) << 3)];
        f16x8 a1 = *(const f16x8*)&P_lds[w][h_a][(32 + ec0) ^ ((h_a & 7) << 3)];
        // B-frags: V[e][dim], dim = nh*16 + (lane&15)
        f16x8 bf0a, bf0b, bf1a, bf1b;
        #pragma unroll
        for (int j = 0; j < 8; j++) {
            int dd0 = dS[w][ec0 + j];
            int dd1 = dS[w][32 + ec0 + j];
            const f16* vp0 = Vb + (size_t)dd0 * 32 + (lane & 15);
            const f16* vp1 = Vb + (size_t)dd1 * 32 + (lane & 15);
            bf0a[j] = vp0[0];  bf0b[j] = vp0[16];
            bf1a[j] = vp1[0];  bf1b[j] = vp1[16];
        }
        asm volatile("" ::: "memory");   // reads complete before next tile's writes
        acc0 = __builtin_amdgcn_mfma_f32_16x16x32_f16(a0, bf0a, acc0, 0, 0, 0);
        acc0 = __builtin_amdgcn_mfma_f32_16x16x32_f16(a1, bf1a, acc0, 0, 0, 0);
        acc1 = __builtin_amdgcn_mfma_f32_16x16x32_f16(a0, bf0b, acc1, 0, 0, 0);
        acc1 = __builtin_amdgcn_mfma_f32_16x16x32_f16(a1, bf1b, acc1, 0, 0, 0);
        accl = __builtin_amdgcn_mfma_f32_16x16x32_f16(a0, ones, accl, 0, 0, 0);
        accl = __builtin_amdgcn_mfma_f32_16x16x32_f16(a1, ones, accl, 0, 0, 0);
    }
    // epilogue: D row = hsel*4 + r = head, col = lane&15; out dim = h*32 + nh*16 + col
    if (lane < 32) {
        float* op = Out + (size_t)row * 256 + (lane & 15);
        #pragma unroll
        for (int r = 0; r < 4; r++) {
            int h = hsel * 4 + r;
            float inv = 1.f / accl[r];
            op[h * 32]      += acc0[r] * inv;
            op[h * 32 + 16] += acc1[r] * inv;
        }
    }
}

// ---------------- launch ----------------
extern "C" void kernel_launch(void* const* d_in, const int* in_sizes, int n_in,
                              void* d_out, int out_size, void* d_ws, size_t ws_size,
                              hipStream_t stream) {
    const float* F  = (const float*)d_in[0];
    const int*   ei = (const int*)d_in[1];
    const float* Wq = (const float*)d_in[2];
    const float* bq = (const float*)d_in[3];
    const float* Wk = (const float*)d_in[4];
    const float* bk = (const float*)d_in[5];
    const float* Ww = (const float*)d_in[6];
    const float* bw = (const float*)d_in[7];
    const float* Wb = (const float*)d_in[8];
    const float* bb = (const float*)d_in[9];
    int n = in_sizes[0] / 256;       // 50000
    int E = in_sizes[1] / 2;
    const int* srcA = ei;
    const int* dstA = ei + E;
    int n_pad = (n + 127) & ~127;
    int Epad = (E + 63) & ~63;

    // workspace carve-out (~133 MB)
    char* wp = (char*)d_ws;
    auto alloc = [&](size_t bytes) { void* p = wp; wp += (bytes + 255) & ~255ull; return p; };
    f16*   sE   = (f16*)alloc((size_t)Epad * 8 * 2);
    f16*   Wc   = (f16*)alloc((size_t)WC_PAD * 256 * 2);
    float* bias = (float*)alloc((size_t)WC_PAD * 4);
    f16*   Qb   = (f16*)alloc((size_t)n * 512 * 2);
    f16*   Kb   = (f16*)alloc((size_t)n * 512 * 2);
    f16*   Vb   = (f16*)alloc((size_t)n * 32 * 2);
    int*   rs   = (int*)alloc((size_t)(n + 1) * 4);
    float* Out  = (float*)d_out;

    prep_weights<<<WC_PAD, 256, 0, stream>>>(Wq, bq, Wk, bk, Ww, bw, Wb, bb, Wc, bias);
    build_rows<<<(E + 255) / 256, 256, 0, stream>>>(srcA, E, n, rs);
    dim3 g(WC_PAD / 128, n_pad / 128);   // N fastest: A-panel L2-reuse, B L2-resident
    gemm_fused<<<g, 256, 0, stream>>>(F, Wc, bias, Qb, Kb, Vb, Out, n);
    int wgph = (E + 127) / 128;          // 128 edges per block per head
    edge_scores<<<8 * wgph, 256, 0, stream>>>(srcA, dstA, Qb, Kb, sE, E, Epad);
    edge_agg<<<(n + 3) / 4, 256, 0, stream>>>(rs, dstA, sE, Vb, Out, n, Epad);
}

// Round 17
// 428.396 us; speedup vs baseline: 1.3184x; 1.0494x over previous
//
#include <hip/hip_runtime.h>
#include <hip/hip_fp16.h>

typedef _Float16 f16;
typedef _Float16 f16x2 __attribute__((ext_vector_type(2)));
typedef _Float16 f16x8 __attribute__((ext_vector_type(8)));
typedef float f32x4 __attribute__((ext_vector_type(4)));

// Combined projection: rows 0..511 = Wq (8 heads x 64), 512..1023 = Wk,
// 1024..1055 = Ww (V), 1056..1311 = Wb (output). Padded to 1408 rows (128-mult).
#define WC_ROWS 1312
#define WC_PAD 1408

// ---------------- prep: combined weight matrix (f16) + bias (f32) ----------------
__global__ void prep_weights(const float* __restrict__ Wq, const float* __restrict__ bq,
                             const float* __restrict__ Wk, const float* __restrict__ bk,
                             const float* __restrict__ Ww, const float* __restrict__ bw,
                             const float* __restrict__ Wb, const float* __restrict__ bb,
                             f16* __restrict__ Wc, float* __restrict__ bias) {
    int id = blockIdx.x * 256 + threadIdx.x;   // WC_PAD*256 threads
    int j = id >> 8, k = id & 255;
    if (j >= WC_PAD) return;
    float v;
    if (j < 512)       v = Wq[j*256 + k];          // Wq flat [8,64,256]: row h*64+d == j
    else if (j < 1024) v = Wk[(j-512)*256 + k];
    else if (j < 1056) v = Ww[(j-1024)*256 + k];
    else if (j < 1312) v = Wb[(j-1056)*256 + k];
    else               v = 0.f;
    Wc[j*256 + k] = (f16)v;
    if (k == 0) {
        float b;
        if (j < 512)       b = bq[j];
        else if (j < 1024) b = bk[j-512];
        else if (j < 1056) b = bw[j-1024];
        else if (j < 1312) b = bb[j-1056];
        else               b = 0.f;
        bias[j] = b;
    }
}

// ---------------- prep: CSR row starts (edges sorted by src; every row non-empty) --
__global__ void build_rows(const int* __restrict__ src, int E, int n, int* __restrict__ rs) {
    int e = blockIdx.x * 256 + threadIdx.x;
    if (e == 0) rs[n] = E;
    if (e < E) {
        if (e == 0 || src[e] != src[e-1]) rs[src[e]] = e;
    }
}

// ---------------- fused projection GEMM (r6-proven reg-staged version) -------------
// __syncthreads() + register staging: 0 tripwire failures (r1-r8, r13-r16).
// NOT reverting to global_load_lds/raw-s_barrier: s_barrier is not an LLVM memory
// fence, so next-tile stages can hoist above it -> cross-wave LDS race (r10/r12).
__device__ __forceinline__ int swz_slot(int row, int c) {
    return row * 4 + (c ^ (row & 3) ^ ((row >> 2) & 3));
}

__device__ __forceinline__ uint4 cvt8(float4 a, float4 b) {
    f16x8 o;
    o[0] = (f16)a.x; o[1] = (f16)a.y; o[2] = (f16)a.z; o[3] = (f16)a.w;
    o[4] = (f16)b.x; o[5] = (f16)b.y; o[6] = (f16)b.z; o[7] = (f16)b.w;
    return __builtin_bit_cast(uint4, o);
}

__launch_bounds__(256)
__global__ void gemm_fused(const float* __restrict__ F, const f16* __restrict__ Wc,
                           const float* __restrict__ bias,
                           f16* __restrict__ Qb, f16* __restrict__ Kb, f16* __restrict__ Vb,
                           float* __restrict__ Out, int n) {
    __shared__ uint4 As4[512];   // 128 rows x 32 k (f16) = 8KB
    __shared__ uint4 Bs4[512];   // 128 rows x 32 k = 8KB
    int t = threadIdx.x;
    int lane = t & 63, w = t >> 6;
    int wm = w >> 1, wn = w & 1;
    long m0 = (long)blockIdx.y * 128;
    int n0 = blockIdx.x * 128;

    f32x4 acc[4][4];
    #pragma unroll
    for (int i = 0; i < 4; i++)
        #pragma unroll
        for (int j = 0; j < 4; j++)
            acc[i][j] = (f32x4){0.f, 0.f, 0.f, 0.f};

    int lrow = t >> 2, lc = t & 3;
    long row0 = m0 + lrow, row1 = m0 + 64 + lrow;
    const float4* Fg0 = (const float4*)(F + row0 * 256 + lc * 8);   // 8 f32 per thread
    const float4* Fg1 = (const float4*)(F + row1 * 256 + lc * 8);
    const uint4*  Bg0 = (const uint4*)(Wc + (long)(n0 + lrow) * 256 + lc * 8);
    const uint4*  Bg1 = (const uint4*)(Wc + (long)(n0 + 64 + lrow) * 256 + lc * 8);
    bool ok0 = row0 < n, ok1 = row1 < n;
    int ws0 = swz_slot(lrow, lc);
    int ws1 = swz_slot(lrow + 64, lc);
    int csw = (lane >> 4) ^ (lane & 3) ^ ((lane >> 2) & 3);
    int arow = wm * 64 + (lane & 15);
    int brow = wn * 64 + (lane & 15);

    float4 fa0 = {}, fb0 = {}, fa1 = {}, fb1 = {};
    if (ok0) { fa0 = Fg0[0]; fb0 = Fg0[1]; }
    if (ok1) { fa1 = Fg1[0]; fb1 = Fg1[1]; }
    uint4 rb0 = Bg0[0], rb1 = Bg1[0];
    for (int kt = 0; kt < 8; ++kt) {
        if (kt) __syncthreads();
        As4[ws0] = cvt8(fa0, fb0);
        As4[ws1] = cvt8(fa1, fb1);
        Bs4[ws0] = rb0;
        Bs4[ws1] = rb1;
        __syncthreads();
        if (kt < 7) {            // prefetch next K-slice (k step 32 f32 = 8 float4)
            if (ok0) { fa0 = Fg0[(kt + 1) * 8]; fb0 = Fg0[(kt + 1) * 8 + 1]; }
            if (ok1) { fa1 = Fg1[(kt + 1) * 8]; fb1 = Fg1[(kt + 1) * 8 + 1]; }
            rb0 = Bg0[(kt + 1) * 4];
            rb1 = Bg1[(kt + 1) * 4];
        }
        f16x8 af[4], bf[4];
        const f16x8* Ap = (const f16x8*)As4;
        const f16x8* Bp = (const f16x8*)Bs4;
        #pragma unroll
        for (int i = 0; i < 4; i++) af[i] = Ap[(arow + i * 16) * 4 + csw];
        #pragma unroll
        for (int j = 0; j < 4; j++) bf[j] = Bp[(brow + j * 16) * 4 + csw];
        #pragma unroll
        for (int i = 0; i < 4; i++)
            #pragma unroll
            for (int j = 0; j < 4; j++)
                acc[i][j] = __builtin_amdgcn_mfma_f32_16x16x32_f16(af[i], bf[j], acc[i][j], 0, 0, 0);
    }

    // epilogue: C row = (lane>>4)*4 + reg (M), col = lane&15 (N)  [m89-verified]
    #pragma unroll
    for (int i = 0; i < 4; i++) {
        long gmb = m0 + wm * 64 + i * 16 + (lane >> 4) * 4;
        #pragma unroll
        for (int j = 0; j < 4; j++) {
            int gn = n0 + wn * 64 + j * 16 + (lane & 15);
            float bv = bias[gn];
            #pragma unroll
            for (int r = 0; r < 4; r++) {
                long gm = gmb + r;
                if (gm >= n) continue;
                float v = acc[i][j][r] + bv;
                if (gn < 512)       Qb[gm * 512 + gn] = (f16)v;
                else if (gn < 1024) Kb[gm * 512 + (gn - 512)] = (f16)v;
                else if (gn < 1056) Vb[gm * 32 + (gn - 1024)] = (f16)v;
                else if (gn < 1312) Out[gm * 256 + (gn - 1056)] = v;
                // gn in [1312,1408): padding, no write
            }
        }
    }
}

// ---------------- f16x2 dot helper ----------------
__device__ __forceinline__ float fd2(unsigned a, unsigned b, float c) {
#if defined(__has_builtin)
#if __has_builtin(__builtin_amdgcn_fdot2)
    return __builtin_amdgcn_fdot2(__builtin_bit_cast(f16x2, a), __builtin_bit_cast(f16x2, b), c, false);
#else
    f16x2 x = __builtin_bit_cast(f16x2, a), y = __builtin_bit_cast(f16x2, b);
    return c + (float)x[0] * (float)y[0] + (float)x[1] * (float)y[1];
#endif
#else
    f16x2 x = __builtin_bit_cast(f16x2, a), y = __builtin_bit_cast(f16x2, b);
    return c + (float)x[0] * (float)y[0] + (float)x[1] * (float)y[1];
#endif
}

// ---------------- phase A v5: chunk-lane coalesced, 4 edges/thread, packed reduce --
// (r16-proven, unchanged.) Lanes j=0..7 read one 128B K line in ONE instruction;
// 4 edges/thread; h = bid&7 head-phasing (per-XCD K working set 6.4MB, FETCH
// 443MB); packed f16x2 group reduction. 236us @ ~90% of the measured miss wall.
__launch_bounds__(256)
__global__ void edge_scores(const int* __restrict__ srcA, const int* __restrict__ dstA,
                            const f16* __restrict__ Qb, const f16* __restrict__ Kb,
                            f16* __restrict__ sE, int E, int Epad) {
    int bid = blockIdx.x;
    int h = bid & 7;                          // head = XCD (round-robin dispatch)
    int j = threadIdx.x & 7;                  // 16B chunk within the head's 128B line
    int g = threadIdx.x >> 3;                 // edge group 0..31
    int e0 = (bid >> 3) * 128 + g;            // edges e0 + 32*u, u=0..3
    int s[4], d[4];
    #pragma unroll
    for (int u = 0; u < 4; u++) {
        int e = e0 + 32 * u;
        bool ok = e < E;
        s[u] = ok ? srcA[e] : 0;
        d[u] = ok ? dstA[e] : 0;
    }
    uint4 kv[4], qv[4];
    #pragma unroll
    for (int u = 0; u < 4; u++)               // 4 gather lines issued back-to-back
        kv[u] = *(const uint4*)(Kb + (size_t)d[u] * 512 + h * 64 + j * 8);
    #pragma unroll
    for (int u = 0; u < 4; u++)               // 4 Q chunks (L1/L2-hot)
        qv[u] = *(const uint4*)(Qb + (size_t)s[u] * 512 + h * 64 + j * 8);
    float aa[4];
    #pragma unroll
    for (int u = 0; u < 4; u++) {
        float a = 0.f;
        a = fd2(qv[u].x, kv[u].x, a);
        a = fd2(qv[u].y, kv[u].y, a);
        a = fd2(qv[u].z, kv[u].z, a);
        a = fd2(qv[u].w, kv[u].w, a);
        aa[u] = a;
    }
    // packed 8-lane-group reduction: 2 regs carry 4 edges' partials
    f16x2 p01, p23;
    p01[0] = (f16)aa[0]; p01[1] = (f16)aa[1];
    p23[0] = (f16)aa[2]; p23[1] = (f16)aa[3];
    unsigned u01 = __builtin_bit_cast(unsigned, p01);
    unsigned u23 = __builtin_bit_cast(unsigned, p23);
    #pragma unroll
    for (int off = 1; off < 8; off <<= 1) {
        unsigned v01 = __shfl_xor(u01, off);
        unsigned v23 = __shfl_xor(u23, off);
        f16x2 r01 = __builtin_bit_cast(f16x2, u01) + __builtin_bit_cast(f16x2, v01);
        f16x2 r23 = __builtin_bit_cast(f16x2, u23) + __builtin_bit_cast(f16x2, v23);
        u01 = __builtin_bit_cast(unsigned, r01);
        u23 = __builtin_bit_cast(unsigned, r23);
    }
    if (j == 0) {
        f16x2 r01 = __builtin_bit_cast(f16x2, u01);
        f16x2 r23 = __builtin_bit_cast(f16x2, u23);
        size_t bo = (size_t)h * Epad;
        if (e0 < E)      sE[bo + e0]      = r01[0];
        if (e0+32 < E)   sE[bo + e0+32]   = r01[1];
        if (e0+64 < E)   sE[bo + e0+64]   = r23[0];
        if (e0+96 < E)   sE[bo + e0+96]   = r23[1];
    }
}

// ---------------- transpose: sE [h][Epad] -> sT [e][8] -----------------------------
// Scores wants [h][Epad] (coalesced head-phased stores); agg wants [e][8] (one
// f16x8 per lane per tile — the r13 layout switch cost agg ~40us in scalar loads).
// Register 8x8 transpose: 8 coalesced f16x8 reads, 8 thread-consecutive 16B writes.
// sT aliases the dead Qb buffer (unused after edge_scores).
__launch_bounds__(256)
__global__ void transpose_sE(const f16* __restrict__ sE, f16* __restrict__ sT,
                             int E, int Epad) {
    long e8 = (long)blockIdx.x * 2048 + (long)threadIdx.x * 8;   // this thread's 8 edges
    if (e8 >= E) return;
    f16x8 rowv[8];
    #pragma unroll
    for (int h = 0; h < 8; h++)
        rowv[h] = *(const f16x8*)(sE + (size_t)h * Epad + e8);   // 8 edges of head h
    #pragma unroll
    for (int u = 0; u < 8; u++) {
        long e = e8 + u;
        if (e < E) {
            f16x8 o;
            #pragma unroll
            for (int h = 0; h < 8; h++) o[h] = rowv[h][u];
            *(f16x8*)(sT + (size_t)e * 8) = o;
        }
    }
}

// ---------------- phase B v3: single-pass online softmax, [e][8] sE ----------------
// r16-proven single-pass structure (tripwire-passed); per-tile sE read is back to
// ONE f16x8 load per lane (r6-style) from the transposed sT.
__launch_bounds__(256)
__global__ void edge_agg(const int* __restrict__ rs, const int* __restrict__ dstA,
                         const f16* __restrict__ sT, const f16* __restrict__ Vb,
                         float* __restrict__ Out, int n) {
    __shared__ __align__(16) f16 P_lds[4][16][64];
    __shared__ int dS[4][64];
    int w = threadIdx.x >> 6, lane = threadIdx.x & 63;
    int row = blockIdx.x * 4 + w;
    if (row >= n) return;
    int e0 = rs[row], deg = rs[row + 1] - e0;
    {   // zero A-frag rows 8..15 (read by MFMA, results discarded; avoid NaN garbage)
        f16x8 z = {};
        *(f16x8*)&P_lds[w][8 + (lane >> 3)][(lane & 7) * 8] = z;
    }
    asm volatile("" ::: "memory");
    float m[8];
    #pragma unroll
    for (int h = 0; h < 8; h++) m[h] = -1e30f;
    f32x4 acc0 = {}, acc1 = {}, accl = {};
    int ec0 = (lane >> 4) * 8, h_a = lane & 15, hsel = (lane >> 4) & 1;
    f16x8 ones;
    #pragma unroll
    for (int j = 0; j < 8; j++) ones[j] = (f16)1.f;

    for (int base = 0; base < deg; base += 64) {
        int nE = deg - base; if (nE > 64) nE = 64;
        bool act = lane < nE;
        int ee = e0 + base + (act ? lane : 0);
        dS[w][lane] = dstA[ee];
        f16x8 s8 = *(const f16x8*)(sT + (size_t)ee * 8);   // all 8 heads, one load
        float sc[8];
        #pragma unroll
        for (int h = 0; h < 8; h++) {
            float sv = act ? (float)s8[h] : -1e30f;
            float tv = sv;
            #pragma unroll
            for (int off = 1; off < 64; off <<= 1) tv = fmaxf(tv, __shfl_xor(tv, off));
            float nm = fmaxf(m[h], tv);
            sc[h] = __expf(m[h] - nm);
            float p = act ? __expf(sv - nm) : 0.f;
            P_lds[w][h][lane ^ (h << 3)] = (f16)p;
            m[h] = nm;
        }
        #pragma unroll
        for (int r = 0; r < 4; r++) {   // rescale accs (head = hsel*4 + r)
            float f = hsel ? sc[r + 4] : sc[r];
            acc0[r] *= f;
            acc1[r] *= f;
            accl[r] *= f;
        }
        asm volatile("" ::: "memory");   // LDS writes ordered before the punned reads
        // A-frags: P[h][k], k = ks*32 + ec0 + j (XOR-decoded contiguous b128)
        f16x8 a0 = *(const f16x8*)&P_lds[w][h_a][(ec0)      ^ ((h_a & 7) << 3)];
        f16x8 a1 = *(const f16x8*)&P_lds[w][h_a][(32 + ec0) ^ ((h_a & 7) << 3)];
        // B-frags: V[e][dim], dim = nh*16 + (lane&15)
        f16x8 bf0a, bf0b, bf1a, bf1b;
        #pragma unroll
        for (int j = 0; j < 8; j++) {
            int dd0 = dS[w][ec0 + j];
            int dd1 = dS[w][32 + ec0 + j];
            const f16* vp0 = Vb + (size_t)dd0 * 32 + (lane & 15);
            const f16* vp1 = Vb + (size_t)dd1 * 32 + (lane & 15);
            bf0a[j] = vp0[0];  bf0b[j] = vp0[16];
            bf1a[j] = vp1[0];  bf1b[j] = vp1[16];
        }
        asm volatile("" ::: "memory");   // reads complete before next tile's writes
        acc0 = __builtin_amdgcn_mfma_f32_16x16x32_f16(a0, bf0a, acc0, 0, 0, 0);
        acc0 = __builtin_amdgcn_mfma_f32_16x16x32_f16(a1, bf1a, acc0, 0, 0, 0);
        acc1 = __builtin_amdgcn_mfma_f32_16x16x32_f16(a0, bf0b, acc1, 0, 0, 0);
        acc1 = __builtin_amdgcn_mfma_f32_16x16x32_f16(a1, bf1b, acc1, 0, 0, 0);
        accl = __builtin_amdgcn_mfma_f32_16x16x32_f16(a0, ones, accl, 0, 0, 0);
        accl = __builtin_amdgcn_mfma_f32_16x16x32_f16(a1, ones, accl, 0, 0, 0);
    }
    // epilogue: D row = hsel*4 + r = head, col = lane&15; out dim = h*32 + nh*16 + col
    if (lane < 32) {
        float* op = Out + (size_t)row * 256 + (lane & 15);
        #pragma unroll
        for (int r = 0; r < 4; r++) {
            int h = hsel * 4 + r;
            float inv = 1.f / accl[r];
            op[h * 32]      += acc0[r] * inv;
            op[h * 32 + 16] += acc1[r] * inv;
        }
    }
}

// ---------------- launch ----------------
extern "C" void kernel_launch(void* const* d_in, const int* in_sizes, int n_in,
                              void* d_out, int out_size, void* d_ws, size_t ws_size,
                              hipStream_t stream) {
    const float* F  = (const float*)d_in[0];
    const int*   ei = (const int*)d_in[1];
    const float* Wq = (const float*)d_in[2];
    const float* bq = (const float*)d_in[3];
    const float* Wk = (const float*)d_in[4];
    const float* bk = (const float*)d_in[5];
    const float* Ww = (const float*)d_in[6];
    const float* bw = (const float*)d_in[7];
    const float* Wb = (const float*)d_in[8];
    const float* bb = (const float*)d_in[9];
    int n = in_sizes[0] / 256;       // 50000
    int E = in_sizes[1] / 2;
    const int* srcA = ei;
    const int* dstA = ei + E;
    int n_pad = (n + 127) & ~127;
    int Epad = (E + 63) & ~63;

    // workspace carve-out (~133 MB); sT aliases Qb (dead after edge_scores)
    char* wp = (char*)d_ws;
    auto alloc = [&](size_t bytes) { void* p = wp; wp += (bytes + 255) & ~255ull; return p; };
    f16*   sE   = (f16*)alloc((size_t)Epad * 8 * 2);
    f16*   Wc   = (f16*)alloc((size_t)WC_PAD * 256 * 2);
    float* bias = (float*)alloc((size_t)WC_PAD * 4);
    f16*   Qb   = (f16*)alloc((size_t)n * 512 * 2);
    f16*   Kb   = (f16*)alloc((size_t)n * 512 * 2);
    f16*   Vb   = (f16*)alloc((size_t)n * 32 * 2);
    int*   rs   = (int*)alloc((size_t)(n + 1) * 4);
    float* Out  = (float*)d_out;
    f16*   sT   = Qb;                // alias: Qb (51MB) >= sT (26MB), dead after scores

    prep_weights<<<WC_PAD, 256, 0, stream>>>(Wq, bq, Wk, bk, Ww, bw, Wb, bb, Wc, bias);
    build_rows<<<(E + 255) / 256, 256, 0, stream>>>(srcA, E, n, rs);
    dim3 g(WC_PAD / 128, n_pad / 128);   // N fastest: A-panel L2-reuse, B L2-resident
    gemm_fused<<<g, 256, 0, stream>>>(F, Wc, bias, Qb, Kb, Vb, Out, n);
    int wgph = (E + 127) / 128;          // 128 edges per block per head
    edge_scores<<<8 * wgph, 256, 0, stream>>>(srcA, dstA, Qb, Kb, sE, E, Epad);
    transpose_sE<<<(int)((E + 2047) / 2048), 256, 0, stream>>>(sE, sT, E, Epad);
    edge_agg<<<(n + 3) / 4, 256, 0, stream>>>(rs, dstA, sT, Vb, Out, n);
}